// Round 12
// baseline (210.867 us; speedup 1.0000x reference)
//
#include <hip/hip_runtime.h>
#include <hip/hip_bf16.h>

typedef __hip_bfloat16 bf16;
typedef unsigned short u16;

#define NB   2
#define NPT  2048
#define NROI 128
#define CINF 256
#define NS   16
#define KDIM 259     // CIN + 3
#define KP2  288     // W_mlp repack stride (cols 0..255 feat, 256..258 xyz, pad)
#define C1   256     // mlp out channels
#define C2   128     // layer1/2 out channels
#define NVOX 125
#define EPSF 1e-5f

typedef __bf16 bf16x8 __attribute__((ext_vector_type(8)));
typedef float  f32x4  __attribute__((ext_vector_type(4)));

__device__ __forceinline__ float ldin(const void* p, size_t i, int f32flag) {
    if (f32flag) return ((const float*)p)[i];
    unsigned short u = ((const unsigned short*)p)[i];
    return __uint_as_float(((unsigned)u) << 16);
}

__device__ __forceinline__ unsigned short f2bf(float x) {
    unsigned u = __float_as_uint(x);
    u += 0x7FFFu + ((u >> 16) & 1u);
    return (unsigned short)(u >> 16);
}

// Inline dtype detect (uniform across threads; see R10 notes).
__device__ __forceinline__ int detect_flag(const void* __restrict__ Wm) {
    const uint4* p = (const uint4*)Wm;
    int bad = 0;
    #pragma unroll
    for (int i = 0; i < 8; i++) {
        uint4 v = p[i];
        unsigned w[4] = {v.x, v.y, v.z, v.w};
        #pragma unroll
        for (int j = 0; j < 4; j++) {
            if (!(fabsf(__uint_as_float(w[j] << 16)) <= 1e4f)) bad = 1;
            if (!(fabsf(__uint_as_float(w[j] & 0xFFFF0000u)) <= 1e4f)) bad = 1;
        }
    }
    return bad;
}

// ---------------- ws layout (float units), total 4,374,544 f = 17.5 MB ----------------
// ptsf@16  roisf@12304  params@14096  Wbf@64528  stats@101392  idxb@102416
// ftbf@167952  Hmax@1216528(h1 overlays)  Hmin@2265104(h2 overlays; fp@2789392)
// psx@3313680 psy@3317776 psz@3321872  Hf@3325968 (glist overlays)

// K_A: fused setup (unchanged)
__global__ __launch_bounds__(256) void k_setup(
    const void* __restrict__ pts, const void* __restrict__ feat, const void* __restrict__ rois,
    const void* __restrict__ Wm, const void* __restrict__ gm, const void* __restrict__ btm,
    const void* __restrict__ W1, const void* __restrict__ b1, const void* __restrict__ g1,
    const void* __restrict__ bt1, const void* __restrict__ W2, const void* __restrict__ b2,
    const void* __restrict__ g2, const void* __restrict__ bt2,
    float* __restrict__ ptsf, float* __restrict__ roisf, float* __restrict__ params,
    u16* __restrict__ wbf, u16* __restrict__ w1bf, u16* __restrict__ w2bf,
    float* __restrict__ stats, u16* __restrict__ ftbf,
    float* __restrict__ psx, float* __restrict__ psy, float* __restrict__ psz) {
    int f = detect_flag(Wm);
    int bx = blockIdx.x;
    int tid = threadIdx.x;
    if (bx < 1024) {
        __shared__ float tile[32][33];
        int b = bx >> 9;
        int r = bx & 511;
        int n0 = (r & 63) * 32, c0 = (r >> 6) * 32;
        int tx = tid & 31, ty = tid >> 5;
        #pragma unroll
        for (int d = 0; d < 4; d++) {
            int c = c0 + ty + d * 8;
            tile[ty + d * 8][tx] = ldin(feat, ((size_t)(b * CINF + c)) * NPT + n0 + tx, f);
        }
        __syncthreads();
        #pragma unroll
        for (int d = 0; d < 4; d++) {
            int n = n0 + ty + d * 8;
            ftbf[((size_t)(b * NPT + n)) * CINF + c0 + tx] = f2bf(tile[tx][ty + d * 8]);
        }
    } else if (bx < 1312) {
        int e = (bx - 1024) * 256 + tid;
        int o = e / KP2, k = e % KP2;
        float v = 0.f;
        if (k < 256)      v = ldin(Wm, (size_t)o * KDIM + 3 + k, f);
        else if (k < 259) v = ldin(Wm, (size_t)o * KDIM + (k - 256), f);
        wbf[e] = f2bf(v);
    } else if (bx < 1440) {
        int e = (bx - 1312) * 256 + tid;
        w1bf[e] = f2bf(ldin(W1, e, f));
    } else if (bx < 1504) {
        int e = (bx - 1440) * 256 + tid;
        w2bf[e] = f2bf(ldin(W2, e, f));
    } else if (bx < 1552) {
        int e = (bx - 1504) * 256 + tid;
        if (e < NB * NPT * 3) ptsf[e] = ldin(pts, e, f);
    } else if (bx < 1559) {
        int e = (bx - 1552) * 256 + tid;
        if (e < NB * NROI * 7) roisf[e] = ldin(rois, e, f);
    } else if (bx < 1567) {
        int t = bx - 1559;
        const void* src; int off, n;
        switch (t) {
            case 0: src = gm;  off = 0;     n = 256; break;
            case 1: src = btm; off = 256;   n = 256; break;
            case 2: src = b1;  off = 33280; n = 128; break;
            case 3: src = g1;  off = 33408; n = 128; break;
            case 4: src = bt1; off = 33536; n = 128; break;
            case 5: src = b2;  off = 50048; n = 128; break;
            case 6: src = g2;  off = 50176; n = 128; break;
            default: src = bt2; off = 50304; n = 128; break;
        }
        if (tid < n) params[off + tid] = ldin(src, tid, f);
    } else if (bx < 1570) {
        int e = (bx - 1567) * 256 + tid;
        if (e < 768) {
            int d = e >> 8, o = e & 255;
            params[25088 + e] = ldin(Wm, (size_t)o * KDIM + d, f);
        }
    } else if (bx < 1586) {
        int e = (bx - 1570) * 256 + tid;
        if (e < NB * NPT) {
            psx[e] = ldin(pts, e * 3 + 0, f);
            psy[e] = ldin(pts, e * 3 + 1, f);
            psz[e] = ldin(pts, e * 3 + 2, f);
        }
    } else {
        int e = (bx - 1586) * 256 + tid;
        if (e < 1024) stats[e] = 0.f;
    }
}

// K_B: fused ball-query + dense GEMM. knn: R10 early-exit restored (the R11
// break-removal was a +15us regression: 1.7x more chunk work, no pipeline win).
__global__ __launch_bounds__(256) void k_qd(const float* __restrict__ psx, const float* __restrict__ psy,
                                            const float* __restrict__ psz, int* __restrict__ idxb,
                                            const u16* __restrict__ ftbf, const u16* __restrict__ wbf,
                                            float* __restrict__ Hf) {
    int bx = blockIdx.x;
    if (bx < 1024) {
        #pragma clang fp contract(off)
        int wid = threadIdx.x >> 6, lane = threadIdx.x & 63;
        int q = bx * 4 + wid;
        int b = q >> 11;
        int base = b * NPT;
        float qx = psx[q], qy = psy[q], qz = psz[q];
        const float R2 = (float)(0.3 * 0.3);
        size_t ob = (size_t)q * NS;
        int cnt = 0, j0 = -1;
        unsigned long long below = (lane == 63) ? ~0ull >> 1 : ((1ull << (lane + 1)) - 1) >> 1;
        for (int c0 = 0; c0 < NPT; c0 += 64) {
            int j = c0 + lane;
            float dx = qx - psx[base + j];
            float dy = qy - psy[base + j];
            float dz = qz - psz[base + j];
            float d2 = dx * dx + dy * dy + dz * dz;
            bool hit = d2 < R2;
            unsigned long long m = __ballot(hit);
            if (m) {
                if (j0 < 0) j0 = c0 + __builtin_ctzll(m);
                int pos = cnt + __popcll(m & below);
                if (hit && pos < NS) idxb[ob + pos] = j;
                cnt += __popcll(m);
            }
            if (cnt >= NS) break;
        }
        if (lane >= cnt && lane < NS) idxb[ob + lane] = j0;
    } else {
        int bx2 = bx - 1024;
        int w = threadIdx.x >> 6, lane = threadIdx.x & 63;
        int lg = lane >> 4, lr = lane & 15;
        int rbase = (bx2 & 255) * 16;
        int c0 = (bx2 >> 8) * 128 + w * 32;

        size_t aoff  = (size_t)(rbase + lr) * CINF + lg * 8;
        size_t boff0 = (size_t)(c0 + lr) * KP2 + lg * 8;
        size_t boff1 = (size_t)(c0 + 16 + lr) * KP2 + lg * 8;

        f32x4 acc0 = (f32x4){0.f, 0.f, 0.f, 0.f};
        f32x4 acc1 = (f32x4){0.f, 0.f, 0.f, 0.f};
        #pragma unroll
        for (int k0 = 0; k0 < 256; k0 += 32) {
            bf16x8 af = __builtin_bit_cast(bf16x8, *(const uint4*)(ftbf + aoff + k0));
            bf16x8 b0 = __builtin_bit_cast(bf16x8, *(const uint4*)(wbf + boff0 + k0));
            bf16x8 b1 = __builtin_bit_cast(bf16x8, *(const uint4*)(wbf + boff1 + k0));
            acc0 = __builtin_amdgcn_mfma_f32_16x16x32_bf16(af, b0, acc0, 0, 0, 0);
            acc1 = __builtin_amdgcn_mfma_f32_16x16x32_bf16(af, b1, acc1, 0, 0, 0);
        }
        #pragma unroll
        for (int r = 0; r < 4; r++) {
            int row = rbase + lg * 4 + r;
            Hf[(size_t)row * C1 + c0 + lr] = acc0[r];
            Hf[(size_t)row * C1 + c0 + 16 + lr] = acc1[r];
        }
    }
}

// K_C: gather-reduce. GPTS 8->2: 2048 blocks = 8192 waves (full occupancy) to
// hide the L2 gather latency that capped R11 at 25% slots / 43us.
#define GPTS 2
__global__ __launch_bounds__(256) void k_gather(const float* __restrict__ Hf, const int* __restrict__ idxb,
                                                const float* __restrict__ ptsf, const float* __restrict__ wxyz,
                                                float* __restrict__ Hmax, float* __restrict__ Hmin,
                                                float* __restrict__ stats) {
    int o = threadIdx.x;
    float wx = wxyz[o], wy = wxyz[256 + o], wz = wxyz[512 + o];
    float ssum = 0.f, ssq = 0.f;
    #pragma unroll
    for (int p = 0; p < GPTS; p++) {
        int pt = blockIdx.x * GPTS + p;
        int b = pt >> 11;
        int base = b * NPT;
        size_t cb = (size_t)pt * 3;
        float cxx = ptsf[cb], cyy = ptsf[cb + 1], czz = ptsf[cb + 2];
        float v[NS];
        #pragma unroll
        for (int s = 0; s < NS; s++) {
            int j = idxb[(size_t)pt * NS + s];            // uniform -> scalar
            size_t jb = ((size_t)(base + j)) * 3;
            float gx = (ptsf[jb]     - cxx) / 0.3f;
            float gy = (ptsf[jb + 1] - cyy) / 0.3f;
            float gz = (ptsf[jb + 2] - czz) / 0.3f;
            v[s] = Hf[(size_t)(base + j) * C1 + o] + wx * gx + wy * gy + wz * gz;
        }
        float mx = -3.4e38f, mn = 3.4e38f;
        #pragma unroll
        for (int s = 0; s < NS; s++) {
            mx = fmaxf(mx, v[s]); mn = fminf(mn, v[s]);
            ssum += v[s]; ssq += v[s] * v[s];
        }
        Hmax[(size_t)pt * C1 + o] = mx;
        Hmin[(size_t)pt * C1 + o] = mn;
    }
    atomicAdd(&stats[o], ssum);
    atomicAdd(&stats[256 + o], ssq);
}

// K_D: layer1 GEMM with fused feats0 prologue (unchanged).
__global__ __launch_bounds__(256) void k_lin1f(const float* __restrict__ Hmax, const float* __restrict__ Hmin,
                                               const float* __restrict__ stats, const float* __restrict__ g,
                                               const float* __restrict__ bt, const u16* __restrict__ Wb,
                                               const float* __restrict__ bias, float* __restrict__ out,
                                               float* __restrict__ sum, float* __restrict__ sumsq) {
    __shared__ __align__(16) u16 xa[16][264];
    int tid = threadIdx.x;
    int rbase = blockIdx.x * 16;
    {
        int c = tid;
        const float inv = 1.f / 65536.f;
        float m = stats[c] * inv;
        float var = fmaxf(stats[256 + c] * inv - m * m, 0.f);
        float a = g[c] / sqrtf(var + EPSF);
        float d = bt[c] - m * a;
        #pragma unroll
        for (int r = 0; r < 16; r++) {
            size_t e = (size_t)(rbase + r) * C1 + c;
            float h = (a > 0.f) ? Hmax[e] : Hmin[e];
            xa[r][c] = f2bf(fmaxf(a * h + d, 0.f));
        }
    }
    __syncthreads();
    int w = tid >> 6, lane = tid & 63;
    int lg = lane >> 4, lr = lane & 15;
    int c0 = w * 32;
    size_t boff0 = (size_t)(c0 + lr) * 256 + lg * 8;
    size_t boff1 = (size_t)(c0 + 16 + lr) * 256 + lg * 8;

    f32x4 acc0 = (f32x4){0.f, 0.f, 0.f, 0.f};
    f32x4 acc1 = (f32x4){0.f, 0.f, 0.f, 0.f};
    #pragma unroll
    for (int k0 = 0; k0 < 256; k0 += 32) {
        bf16x8 af = __builtin_bit_cast(bf16x8, *(const uint4*)&xa[lr][k0 + lg * 8]);
        bf16x8 b0 = __builtin_bit_cast(bf16x8, *(const uint4*)(Wb + boff0 + k0));
        bf16x8 b1 = __builtin_bit_cast(bf16x8, *(const uint4*)(Wb + boff1 + k0));
        acc0 = __builtin_amdgcn_mfma_f32_16x16x32_bf16(af, b0, acc0, 0, 0, 0);
        acc1 = __builtin_amdgcn_mfma_f32_16x16x32_bf16(af, b1, acc1, 0, 0, 0);
    }
    #pragma unroll
    for (int ct = 0; ct < 2; ct++) {
        f32x4 a = ct ? acc1 : acc0;
        int col = c0 + ct * 16 + lr;
        float bi = bias[col];
        float s = 0.f, q = 0.f;
        #pragma unroll
        for (int r = 0; r < 4; r++) {
            float h = a[r] + bi;
            out[(size_t)(rbase + lg * 4 + r) * C2 + col] = h;
            s += h; q += h * h;
        }
        s += __shfl_xor(s, 16); s += __shfl_xor(s, 32);
        q += __shfl_xor(q, 16); q += __shfl_xor(q, 32);
        if (lane < 16) {
            atomicAdd(&sum[col], s);
            atomicAdd(&sumsq[col], q);
        }
    }
}

// K_E: layer2 GEMM with fused bnrelu prologue (unchanged).
__global__ __launch_bounds__(256) void k_lin2f(const float* __restrict__ h1, const float* __restrict__ stats1,
                                               const float* __restrict__ g, const float* __restrict__ bt,
                                               const u16* __restrict__ Wb, const float* __restrict__ bias,
                                               float* __restrict__ out, float* __restrict__ sum,
                                               float* __restrict__ sumsq) {
    __shared__ __align__(16) u16 xa[16][136];
    int tid = threadIdx.x;
    int rbase = blockIdx.x * 16;
    {
        int c = tid & 127, half = tid >> 7;
        const float inv = 1.f / 4096.f;
        float m = stats1[c] * inv;
        float var = fmaxf(stats1[128 + c] * inv - m * m, 0.f);
        float a = g[c] / sqrtf(var + EPSF);
        float d = bt[c] - m * a;
        #pragma unroll
        for (int rr = 0; rr < 8; rr++) {
            int r = half * 8 + rr;
            float h = h1[(size_t)(rbase + r) * C2 + c];
            xa[r][c] = f2bf(fmaxf(a * h + d, 0.f));
        }
    }
    __syncthreads();
    int w = tid >> 6, lane = tid & 63;
    int lg = lane >> 4, lr = lane & 15;
    int c0 = w * 32;
    size_t boff0 = (size_t)(c0 + lr) * 128 + lg * 8;
    size_t boff1 = (size_t)(c0 + 16 + lr) * 128 + lg * 8;

    f32x4 acc0 = (f32x4){0.f, 0.f, 0.f, 0.f};
    f32x4 acc1 = (f32x4){0.f, 0.f, 0.f, 0.f};
    #pragma unroll
    for (int k0 = 0; k0 < 128; k0 += 32) {
        bf16x8 af = __builtin_bit_cast(bf16x8, *(const uint4*)&xa[lr][k0 + lg * 8]);
        bf16x8 b0 = __builtin_bit_cast(bf16x8, *(const uint4*)(Wb + boff0 + k0));
        bf16x8 b1 = __builtin_bit_cast(bf16x8, *(const uint4*)(Wb + boff1 + k0));
        acc0 = __builtin_amdgcn_mfma_f32_16x16x32_bf16(af, b0, acc0, 0, 0, 0);
        acc1 = __builtin_amdgcn_mfma_f32_16x16x32_bf16(af, b1, acc1, 0, 0, 0);
    }
    #pragma unroll
    for (int ct = 0; ct < 2; ct++) {
        f32x4 a = ct ? acc1 : acc0;
        int col = c0 + ct * 16 + lr;
        float bi = bias[col];
        float s = 0.f, q = 0.f;
        #pragma unroll
        for (int r = 0; r < 4; r++) {
            float h = a[r] + bi;
            out[(size_t)(rbase + lg * 4 + r) * C2 + col] = h;
            s += h; q += h * h;
        }
        s += __shfl_xor(s, 16); s += __shfl_xor(s, 32);
        q += __shfl_xor(q, 16); q += __shfl_xor(q, 32);
        if (lane < 16) {
            atomicAdd(&sum[col], s);
            atomicAdd(&sumsq[col], q);
        }
    }
}

// K_F v2: relu(BN(h2)) with LDS-transposed out0 write (unchanged).
__global__ __launch_bounds__(256) void k_final2(const float* __restrict__ h2, const float* __restrict__ sum,
                                                const float* __restrict__ sumsq, const float* __restrict__ g,
                                                const float* __restrict__ bt, float* __restrict__ fp,
                                                void* __restrict__ out0, const void* __restrict__ Wm) {
    __shared__ float tile[64][65];
    __shared__ float aL[64], dL[64];
    int f = detect_flag(Wm);
    int bx = blockIdx.x;
    int b = bx >> 6;
    int rem = bx & 63;
    int n0 = (rem >> 1) * 64;
    int o0 = (rem & 1) * 64;
    int tid = threadIdx.x;
    if (tid < 64) {
        int o = o0 + tid;
        const float inv = 1.f / 4096.f;
        float m = sum[o] * inv;
        float var = fmaxf(sumsq[o] * inv - m * m, 0.f);
        float a = g[o] / sqrtf(var + EPSF);
        aL[tid] = a;
        dL[tid] = bt[o] - m * a;
    }
    __syncthreads();
    #pragma unroll
    for (int it = 0; it < 16; it++) {
        int idx = it * 256 + tid;
        int nn = idx >> 6, oo = idx & 63;
        size_t e = (size_t)(b * NPT + n0 + nn) * C2 + o0 + oo;
        float v = fmaxf(aL[oo] * h2[e] + dL[oo], 0.f);
        fp[e] = v;
        tile[nn][oo] = v;
    }
    __syncthreads();
    #pragma unroll
    for (int it = 0; it < 16; it++) {
        int idx = it * 256 + tid;
        int oo = idx >> 6, nn = idx & 63;
        size_t oi = ((size_t)(b * C2 + o0 + oo)) * NPT + n0 + nn;
        float v = tile[nn][oo];
        if (f) ((float*)out0)[oi] = v;
        else   ((unsigned short*)out0)[oi] = f2bf(v);
    }
}

// K_G: RoI voxel max-pool (unchanged from R11).
__global__ __launch_bounds__(512) void k_pool2(const float* __restrict__ ptsf, const float* __restrict__ roisf,
                                               const float* __restrict__ fp, void* __restrict__ d_out,
                                               const void* __restrict__ Wm, int* __restrict__ glist) {
    #pragma clang fp contract(off)
    __shared__ __align__(16) int pooled[NVOX * C2];   // 64000 B
    __shared__ int cnt;
    __shared__ float rp[8];
    int f = detect_flag(Wm);
    int bid = blockIdx.x;
    int b = bid >> 7;
    int tid = threadIdx.x;
    for (int k = tid; k < NVOX * C2 / 4; k += 512) ((int4*)pooled)[k] = (int4){0, 0, 0, 0};
    if (tid == 0) {
        cnt = 0;
        size_t rb = ((size_t)bid) * 7;
        rp[0] = roisf[rb];     rp[1] = roisf[rb + 1]; rp[2] = roisf[rb + 2];
        rp[3] = roisf[rb + 3] * 0.5f;
        rp[4] = roisf[rb + 4] * 0.5f;
        rp[5] = roisf[rb + 5] * 0.5f;
        float ry = roisf[rb + 6];
        rp[6] = (float)cos((double)ry);
        rp[7] = (float)sin((double)ry);
    }
    __syncthreads();
    float cx = rp[0], cy = rp[1], cz = rp[2];
    float hx = rp[3], hy = rp[4], hz = rp[5];
    float cf = rp[6], sf = rp[7];
    int* mylist = glist + bid * NPT;
    for (int n = tid; n < NPT; n += 512) {
        size_t pb = ((size_t)(b * NPT + n)) * 3;
        float rx  = ptsf[pb]     - cx;
        float ryy = ptsf[pb + 1] - cy;
        float rz  = ptsf[pb + 2] - cz;
        float lx = rx * cf + ryy * sf;
        float ly = -rx * sf + ryy * cf;
        if (fabsf(lx) < hx && fabsf(ly) < hy && fabsf(rz) < hz) {
            int vx = (int)fminf(fmaxf(floorf((lx + hx) / (2.f * hx) * 5.f), 0.f), 4.f);
            int vy = (int)fminf(fmaxf(floorf((ly + hy) / (2.f * hy) * 5.f), 0.f), 4.f);
            int vz = (int)fminf(fmaxf(floorf((rz + hz) / (2.f * hz) * 5.f), 0.f), 4.f);
            int vox = (vx * 5 + vy) * 5 + vz;
            int pos = atomicAdd(&cnt, 1);
            mylist[pos] = (vox << 16) | n;
        }
    }
    __syncthreads();
    int m = cnt;
    int c = tid & 127, slot = tid >> 7;
    for (int e = slot; e < m; e += 4) {
        int u = mylist[e];
        int n = u & 0xFFFF, vox = u >> 16;
        float v = fp[((size_t)(b * NPT + n)) * C2 + c];
        atomicMax(&pooled[vox * C2 + c], __float_as_int(v));
    }
    __syncthreads();
    size_t ob = (size_t)524288 + (size_t)bid * (NVOX * C2);
    if (f) {
        for (int k4 = tid; k4 < NVOX * C2 / 4; k4 += 512) {
            int4 w = ((const int4*)pooled)[k4];
            float4 v = {__int_as_float(w.x), __int_as_float(w.y), __int_as_float(w.z), __int_as_float(w.w)};
            *(float4*)((float*)d_out + ob + k4 * 4) = v;
        }
    } else {
        for (int k4 = tid; k4 < NVOX * C2 / 4; k4 += 512) {
            int4 w = ((const int4*)pooled)[k4];
            ushort4 v = {f2bf(__int_as_float(w.x)), f2bf(__int_as_float(w.y)),
                         f2bf(__int_as_float(w.z)), f2bf(__int_as_float(w.w))};
            *(ushort4*)((unsigned short*)d_out + ob + k4 * 4) = v;
        }
    }
}

extern "C" void kernel_launch(void* const* d_in, const int* in_sizes, int n_in,
                              void* d_out, int out_size, void* d_ws, size_t ws_size,
                              hipStream_t stream) {
    const void* pts  = d_in[0];
    const void* feat = d_in[1];
    const void* rois = d_in[2];
    const void* Wm   = d_in[3];
    const void* gm   = d_in[4];
    const void* btm  = d_in[5];
    const void* W1   = d_in[6];
    const void* b1   = d_in[7];
    const void* g1   = d_in[8];
    const void* bt1  = d_in[9];
    const void* W2   = d_in[10];
    const void* b2   = d_in[11];
    const void* g2   = d_in[12];
    const void* bt2  = d_in[13];

    float* ws     = (float*)d_ws;
    float* ptsf   = ws + 16;
    float* roisf  = ws + 12304;
    float* params = ws + 14096;
    u16*   w1bf   = (u16*)(params + 512);
    u16*   w2bf   = (u16*)(params + 512 + 16384);
    float* wxyz   = params + 25088;
    u16*   wbf    = (u16*)(ws + 64528);
    float* stats  = ws + 101392;
    int*   idxb   = (int*)(ws + 102416);
    u16*   ftbf   = (u16*)(ws + 167952);
    float* Hmax   = ws + 1216528;
    float* Hmin   = ws + 2265104;
    float* h1     = ws + 1216528;
    float* h2     = ws + 2265104;
    float* fp     = ws + 2789392;
    float* psx    = ws + 3313680;
    float* psy    = ws + 3317776;
    float* psz    = ws + 3321872;
    float* Hf     = ws + 3325968;
    int*   glist  = (int*)(ws + 3325968);

    k_setup<<<1590, 256, 0, stream>>>(pts, feat, rois, Wm, gm, btm, W1, b1, g1, bt1,
                                      W2, b2, g2, bt2, ptsf, roisf, params,
                                      wbf, w1bf, w2bf, stats, ftbf, psx, psy, psz);
    k_qd<<<1536, 256, 0, stream>>>(psx, psy, psz, idxb, ftbf, wbf, Hf);
    k_gather<<<(NB * NPT) / GPTS, 256, 0, stream>>>(Hf, idxb, ptsf, wxyz, Hmax, Hmin, stats);
    k_lin1f<<<256, 256, 0, stream>>>(Hmax, Hmin, stats, params + 0, params + 256,
                                     w1bf, params + 33280, h1, stats + 512, stats + 640);
    k_lin2f<<<256, 256, 0, stream>>>(h1, stats + 512, params + 33408, params + 33536,
                                     w2bf, params + 50048, h2, stats + 768, stats + 896);
    k_final2<<<128, 256, 0, stream>>>(h2, stats + 768, stats + 896,
                                      params + 50176, params + 50304, fp, d_out, Wm);
    k_pool2<<<NB * NROI, 512, 0, stream>>>(ptsf, roisf, fp, d_out, Wm, glist);
}

// Round 13
// 189.952 us; speedup vs baseline: 1.1101x; 1.1101x over previous
//
#include <hip/hip_runtime.h>
#include <hip/hip_bf16.h>

typedef __hip_bfloat16 bf16;
typedef unsigned short u16;

#define NB   2
#define NPT  2048
#define NROI 128
#define CINF 256
#define NS   16
#define KDIM 259     // CIN + 3
#define KP2  288     // W_mlp repack stride (cols 0..255 feat, 256..258 xyz, pad)
#define C1   256     // mlp out channels
#define C2   128     // layer1/2 out channels
#define NVOX 125
#define EPSF 1e-5f

typedef __bf16 bf16x8 __attribute__((ext_vector_type(8)));
typedef float  f32x4  __attribute__((ext_vector_type(4)));

__device__ __forceinline__ float ldin(const void* p, size_t i, int f32flag) {
    if (f32flag) return ((const float*)p)[i];
    unsigned short u = ((const unsigned short*)p)[i];
    return __uint_as_float(((unsigned)u) << 16);
}

__device__ __forceinline__ unsigned short f2bf(float x) {
    unsigned u = __float_as_uint(x);
    u += 0x7FFFu + ((u >> 16) & 1u);
    return (unsigned short)(u >> 16);
}

// Inline dtype detect (uniform across threads; see R10 notes).
__device__ __forceinline__ int detect_flag(const void* __restrict__ Wm) {
    const uint4* p = (const uint4*)Wm;
    int bad = 0;
    #pragma unroll
    for (int i = 0; i < 8; i++) {
        uint4 v = p[i];
        unsigned w[4] = {v.x, v.y, v.z, v.w};
        #pragma unroll
        for (int j = 0; j < 4; j++) {
            if (!(fabsf(__uint_as_float(w[j] << 16)) <= 1e4f)) bad = 1;
            if (!(fabsf(__uint_as_float(w[j] & 0xFFFF0000u)) <= 1e4f)) bad = 1;
        }
    }
    return bad;
}

// ---------------- ws layout (float units), total 4,374,544 f = 17.5 MB ----------------
// ptsf@16  roisf@12304  params@14096  Wbf@64528  stats@101392  idxb@102416
// ftbf@167952  Hmax@1216528(h1 overlays)  Hmin@2265104(h2 overlays; fp@2789392)
// psx@3313680 psy@3317776 psz@3321872  Hf@3325968 (glist overlays)

// K_A: fused setup (unchanged)
__global__ __launch_bounds__(256) void k_setup(
    const void* __restrict__ pts, const void* __restrict__ feat, const void* __restrict__ rois,
    const void* __restrict__ Wm, const void* __restrict__ gm, const void* __restrict__ btm,
    const void* __restrict__ W1, const void* __restrict__ b1, const void* __restrict__ g1,
    const void* __restrict__ bt1, const void* __restrict__ W2, const void* __restrict__ b2,
    const void* __restrict__ g2, const void* __restrict__ bt2,
    float* __restrict__ ptsf, float* __restrict__ roisf, float* __restrict__ params,
    u16* __restrict__ wbf, u16* __restrict__ w1bf, u16* __restrict__ w2bf,
    float* __restrict__ stats, u16* __restrict__ ftbf,
    float* __restrict__ psx, float* __restrict__ psy, float* __restrict__ psz) {
    int f = detect_flag(Wm);
    int bx = blockIdx.x;
    int tid = threadIdx.x;
    if (bx < 1024) {
        __shared__ float tile[32][33];
        int b = bx >> 9;
        int r = bx & 511;
        int n0 = (r & 63) * 32, c0 = (r >> 6) * 32;
        int tx = tid & 31, ty = tid >> 5;
        #pragma unroll
        for (int d = 0; d < 4; d++) {
            int c = c0 + ty + d * 8;
            tile[ty + d * 8][tx] = ldin(feat, ((size_t)(b * CINF + c)) * NPT + n0 + tx, f);
        }
        __syncthreads();
        #pragma unroll
        for (int d = 0; d < 4; d++) {
            int n = n0 + ty + d * 8;
            ftbf[((size_t)(b * NPT + n)) * CINF + c0 + tx] = f2bf(tile[tx][ty + d * 8]);
        }
    } else if (bx < 1312) {
        int e = (bx - 1024) * 256 + tid;
        int o = e / KP2, k = e % KP2;
        float v = 0.f;
        if (k < 256)      v = ldin(Wm, (size_t)o * KDIM + 3 + k, f);
        else if (k < 259) v = ldin(Wm, (size_t)o * KDIM + (k - 256), f);
        wbf[e] = f2bf(v);
    } else if (bx < 1440) {
        int e = (bx - 1312) * 256 + tid;
        w1bf[e] = f2bf(ldin(W1, e, f));
    } else if (bx < 1504) {
        int e = (bx - 1440) * 256 + tid;
        w2bf[e] = f2bf(ldin(W2, e, f));
    } else if (bx < 1552) {
        int e = (bx - 1504) * 256 + tid;
        if (e < NB * NPT * 3) ptsf[e] = ldin(pts, e, f);
    } else if (bx < 1559) {
        int e = (bx - 1552) * 256 + tid;
        if (e < NB * NROI * 7) roisf[e] = ldin(rois, e, f);
    } else if (bx < 1567) {
        int t = bx - 1559;
        const void* src; int off, n;
        switch (t) {
            case 0: src = gm;  off = 0;     n = 256; break;
            case 1: src = btm; off = 256;   n = 256; break;
            case 2: src = b1;  off = 33280; n = 128; break;
            case 3: src = g1;  off = 33408; n = 128; break;
            case 4: src = bt1; off = 33536; n = 128; break;
            case 5: src = b2;  off = 50048; n = 128; break;
            case 6: src = g2;  off = 50176; n = 128; break;
            default: src = bt2; off = 50304; n = 128; break;
        }
        if (tid < n) params[off + tid] = ldin(src, tid, f);
    } else if (bx < 1570) {
        int e = (bx - 1567) * 256 + tid;
        if (e < 768) {
            int d = e >> 8, o = e & 255;
            params[25088 + e] = ldin(Wm, (size_t)o * KDIM + d, f);
        }
    } else if (bx < 1586) {
        int e = (bx - 1570) * 256 + tid;
        if (e < NB * NPT) {
            psx[e] = ldin(pts, e * 3 + 0, f);
            psy[e] = ldin(pts, e * 3 + 1, f);
            psz[e] = ldin(pts, e * 3 + 2, f);
        }
    } else {
        int e = (bx - 1586) * 256 + tid;
        if (e < 1024) stats[e] = 0.f;
    }
}

// K_B: fused ball-query (with early exit) + dense GEMM (unchanged from R12).
__global__ __launch_bounds__(256) void k_qd(const float* __restrict__ psx, const float* __restrict__ psy,
                                            const float* __restrict__ psz, int* __restrict__ idxb,
                                            const u16* __restrict__ ftbf, const u16* __restrict__ wbf,
                                            float* __restrict__ Hf) {
    int bx = blockIdx.x;
    if (bx < 1024) {
        #pragma clang fp contract(off)
        int wid = threadIdx.x >> 6, lane = threadIdx.x & 63;
        int q = bx * 4 + wid;
        int b = q >> 11;
        int base = b * NPT;
        float qx = psx[q], qy = psy[q], qz = psz[q];
        const float R2 = (float)(0.3 * 0.3);
        size_t ob = (size_t)q * NS;
        int cnt = 0, j0 = -1;
        unsigned long long below = (lane == 63) ? ~0ull >> 1 : ((1ull << (lane + 1)) - 1) >> 1;
        for (int c0 = 0; c0 < NPT; c0 += 64) {
            int j = c0 + lane;
            float dx = qx - psx[base + j];
            float dy = qy - psy[base + j];
            float dz = qz - psz[base + j];
            float d2 = dx * dx + dy * dy + dz * dz;
            bool hit = d2 < R2;
            unsigned long long m = __ballot(hit);
            if (m) {
                if (j0 < 0) j0 = c0 + __builtin_ctzll(m);
                int pos = cnt + __popcll(m & below);
                if (hit && pos < NS) idxb[ob + pos] = j;
                cnt += __popcll(m);
            }
            if (cnt >= NS) break;
        }
        if (lane >= cnt && lane < NS) idxb[ob + lane] = j0;
    } else {
        int bx2 = bx - 1024;
        int w = threadIdx.x >> 6, lane = threadIdx.x & 63;
        int lg = lane >> 4, lr = lane & 15;
        int rbase = (bx2 & 255) * 16;
        int c0 = (bx2 >> 8) * 128 + w * 32;

        size_t aoff  = (size_t)(rbase + lr) * CINF + lg * 8;
        size_t boff0 = (size_t)(c0 + lr) * KP2 + lg * 8;
        size_t boff1 = (size_t)(c0 + 16 + lr) * KP2 + lg * 8;

        f32x4 acc0 = (f32x4){0.f, 0.f, 0.f, 0.f};
        f32x4 acc1 = (f32x4){0.f, 0.f, 0.f, 0.f};
        #pragma unroll
        for (int k0 = 0; k0 < 256; k0 += 32) {
            bf16x8 af = __builtin_bit_cast(bf16x8, *(const uint4*)(ftbf + aoff + k0));
            bf16x8 b0 = __builtin_bit_cast(bf16x8, *(const uint4*)(wbf + boff0 + k0));
            bf16x8 b1 = __builtin_bit_cast(bf16x8, *(const uint4*)(wbf + boff1 + k0));
            acc0 = __builtin_amdgcn_mfma_f32_16x16x32_bf16(af, b0, acc0, 0, 0, 0);
            acc1 = __builtin_amdgcn_mfma_f32_16x16x32_bf16(af, b1, acc1, 0, 0, 0);
        }
        #pragma unroll
        for (int r = 0; r < 4; r++) {
            int row = rbase + lg * 4 + r;
            Hf[(size_t)row * C1 + c0 + lr] = acc0[r];
            Hf[(size_t)row * C1 + c0 + 16 + lr] = acc1[r];
        }
    }
}

// K_C: gather-reduce v3 — s-outer / p-inner for memory-level parallelism.
// Per s-step: 8 INDEPENDENT Hf-row loads (distinct registers) issued before any
// use; running max/min/sum/sq per point (s-order preserved). GPTS back to 8
// (R12's GPTS=2 quadrupled stats-atomic contention). R12's VGPR=20 showed the
// compiler serialized the 16 per-point loads — this structure forces ~80 VGPRs
// and 8-deep load pipelining.
#define GPTS 8
__global__ __launch_bounds__(256) void k_gather(const float* __restrict__ Hf, const int* __restrict__ idxb,
                                                const float* __restrict__ ptsf, const float* __restrict__ wxyz,
                                                float* __restrict__ Hmax, float* __restrict__ Hmin,
                                                float* __restrict__ stats) {
    int o = threadIdx.x;
    float wx = wxyz[o], wy = wxyz[256 + o], wz = wxyz[512 + o];
    int pt0 = blockIdx.x * GPTS;
    int b = pt0 >> 11;
    int base = b * NPT;
    float cx[GPTS], cy[GPTS], cz[GPTS];
    float mx[GPTS], mn[GPTS], sm[GPTS], sq[GPTS];
    #pragma unroll
    for (int p = 0; p < GPTS; p++) {
        size_t cb = (size_t)(pt0 + p) * 3;
        cx[p] = ptsf[cb]; cy[p] = ptsf[cb + 1]; cz[p] = ptsf[cb + 2];
        mx[p] = -3.4e38f; mn[p] = 3.4e38f; sm[p] = 0.f; sq[p] = 0.f;
    }
    for (int s = 0; s < NS; s++) {
        int jj[GPTS];
        float v[GPTS];
        #pragma unroll
        for (int p = 0; p < GPTS; p++)
            jj[p] = idxb[(size_t)(pt0 + p) * NS + s];          // uniform -> scalar loads
        #pragma unroll
        for (int p = 0; p < GPTS; p++)
            v[p] = Hf[(size_t)(base + jj[p]) * C1 + o];        // 8 independent vector loads
        #pragma unroll
        for (int p = 0; p < GPTS; p++) {
            size_t jb = ((size_t)(base + jj[p])) * 3;
            float gx = (ptsf[jb]     - cx[p]) / 0.3f;
            float gy = (ptsf[jb + 1] - cy[p]) / 0.3f;
            float gz = (ptsf[jb + 2] - cz[p]) / 0.3f;
            float t = v[p] + wx * gx + wy * gy + wz * gz;
            mx[p] = fmaxf(mx[p], t); mn[p] = fminf(mn[p], t);
            sm[p] += t; sq[p] += t * t;
        }
    }
    float ssum = 0.f, ssq = 0.f;
    #pragma unroll
    for (int p = 0; p < GPTS; p++) {
        Hmax[(size_t)(pt0 + p) * C1 + o] = mx[p];
        Hmin[(size_t)(pt0 + p) * C1 + o] = mn[p];
        ssum += sm[p]; ssq += sq[p];
    }
    atomicAdd(&stats[o], ssum);
    atomicAdd(&stats[256 + o], ssq);
}

// K_D: layer1 GEMM with fused feats0 prologue (unchanged).
__global__ __launch_bounds__(256) void k_lin1f(const float* __restrict__ Hmax, const float* __restrict__ Hmin,
                                               const float* __restrict__ stats, const float* __restrict__ g,
                                               const float* __restrict__ bt, const u16* __restrict__ Wb,
                                               const float* __restrict__ bias, float* __restrict__ out,
                                               float* __restrict__ sum, float* __restrict__ sumsq) {
    __shared__ __align__(16) u16 xa[16][264];
    int tid = threadIdx.x;
    int rbase = blockIdx.x * 16;
    {
        int c = tid;
        const float inv = 1.f / 65536.f;
        float m = stats[c] * inv;
        float var = fmaxf(stats[256 + c] * inv - m * m, 0.f);
        float a = g[c] / sqrtf(var + EPSF);
        float d = bt[c] - m * a;
        #pragma unroll
        for (int r = 0; r < 16; r++) {
            size_t e = (size_t)(rbase + r) * C1 + c;
            float h = (a > 0.f) ? Hmax[e] : Hmin[e];
            xa[r][c] = f2bf(fmaxf(a * h + d, 0.f));
        }
    }
    __syncthreads();
    int w = tid >> 6, lane = tid & 63;
    int lg = lane >> 4, lr = lane & 15;
    int c0 = w * 32;
    size_t boff0 = (size_t)(c0 + lr) * 256 + lg * 8;
    size_t boff1 = (size_t)(c0 + 16 + lr) * 256 + lg * 8;

    f32x4 acc0 = (f32x4){0.f, 0.f, 0.f, 0.f};
    f32x4 acc1 = (f32x4){0.f, 0.f, 0.f, 0.f};
    #pragma unroll
    for (int k0 = 0; k0 < 256; k0 += 32) {
        bf16x8 af = __builtin_bit_cast(bf16x8, *(const uint4*)&xa[lr][k0 + lg * 8]);
        bf16x8 b0 = __builtin_bit_cast(bf16x8, *(const uint4*)(Wb + boff0 + k0));
        bf16x8 b1 = __builtin_bit_cast(bf16x8, *(const uint4*)(Wb + boff1 + k0));
        acc0 = __builtin_amdgcn_mfma_f32_16x16x32_bf16(af, b0, acc0, 0, 0, 0);
        acc1 = __builtin_amdgcn_mfma_f32_16x16x32_bf16(af, b1, acc1, 0, 0, 0);
    }
    #pragma unroll
    for (int ct = 0; ct < 2; ct++) {
        f32x4 a = ct ? acc1 : acc0;
        int col = c0 + ct * 16 + lr;
        float bi = bias[col];
        float s = 0.f, q = 0.f;
        #pragma unroll
        for (int r = 0; r < 4; r++) {
            float h = a[r] + bi;
            out[(size_t)(rbase + lg * 4 + r) * C2 + col] = h;
            s += h; q += h * h;
        }
        s += __shfl_xor(s, 16); s += __shfl_xor(s, 32);
        q += __shfl_xor(q, 16); q += __shfl_xor(q, 32);
        if (lane < 16) {
            atomicAdd(&sum[col], s);
            atomicAdd(&sumsq[col], q);
        }
    }
}

// K_E: layer2 GEMM with fused bnrelu prologue (unchanged).
__global__ __launch_bounds__(256) void k_lin2f(const float* __restrict__ h1, const float* __restrict__ stats1,
                                               const float* __restrict__ g, const float* __restrict__ bt,
                                               const u16* __restrict__ Wb, const float* __restrict__ bias,
                                               float* __restrict__ out, float* __restrict__ sum,
                                               float* __restrict__ sumsq) {
    __shared__ __align__(16) u16 xa[16][136];
    int tid = threadIdx.x;
    int rbase = blockIdx.x * 16;
    {
        int c = tid & 127, half = tid >> 7;
        const float inv = 1.f / 4096.f;
        float m = stats1[c] * inv;
        float var = fmaxf(stats1[128 + c] * inv - m * m, 0.f);
        float a = g[c] / sqrtf(var + EPSF);
        float d = bt[c] - m * a;
        #pragma unroll
        for (int rr = 0; rr < 8; rr++) {
            int r = half * 8 + rr;
            float h = h1[(size_t)(rbase + r) * C2 + c];
            xa[r][c] = f2bf(fmaxf(a * h + d, 0.f));
        }
    }
    __syncthreads();
    int w = tid >> 6, lane = tid & 63;
    int lg = lane >> 4, lr = lane & 15;
    int c0 = w * 32;
    size_t boff0 = (size_t)(c0 + lr) * 128 + lg * 8;
    size_t boff1 = (size_t)(c0 + 16 + lr) * 128 + lg * 8;

    f32x4 acc0 = (f32x4){0.f, 0.f, 0.f, 0.f};
    f32x4 acc1 = (f32x4){0.f, 0.f, 0.f, 0.f};
    #pragma unroll
    for (int k0 = 0; k0 < 128; k0 += 32) {
        bf16x8 af = __builtin_bit_cast(bf16x8, *(const uint4*)&xa[lr][k0 + lg * 8]);
        bf16x8 b0 = __builtin_bit_cast(bf16x8, *(const uint4*)(Wb + boff0 + k0));
        bf16x8 b1 = __builtin_bit_cast(bf16x8, *(const uint4*)(Wb + boff1 + k0));
        acc0 = __builtin_amdgcn_mfma_f32_16x16x32_bf16(af, b0, acc0, 0, 0, 0);
        acc1 = __builtin_amdgcn_mfma_f32_16x16x32_bf16(af, b1, acc1, 0, 0, 0);
    }
    #pragma unroll
    for (int ct = 0; ct < 2; ct++) {
        f32x4 a = ct ? acc1 : acc0;
        int col = c0 + ct * 16 + lr;
        float bi = bias[col];
        float s = 0.f, q = 0.f;
        #pragma unroll
        for (int r = 0; r < 4; r++) {
            float h = a[r] + bi;
            out[(size_t)(rbase + lg * 4 + r) * C2 + col] = h;
            s += h; q += h * h;
        }
        s += __shfl_xor(s, 16); s += __shfl_xor(s, 32);
        q += __shfl_xor(q, 16); q += __shfl_xor(q, 32);
        if (lane < 16) {
            atomicAdd(&sum[col], s);
            atomicAdd(&sumsq[col], q);
        }
    }
}

// K_F v2: relu(BN(h2)) with LDS-transposed out0 write (unchanged).
__global__ __launch_bounds__(256) void k_final2(const float* __restrict__ h2, const float* __restrict__ sum,
                                                const float* __restrict__ sumsq, const float* __restrict__ g,
                                                const float* __restrict__ bt, float* __restrict__ fp,
                                                void* __restrict__ out0, const void* __restrict__ Wm) {
    __shared__ float tile[64][65];
    __shared__ float aL[64], dL[64];
    int f = detect_flag(Wm);
    int bx = blockIdx.x;
    int b = bx >> 6;
    int rem = bx & 63;
    int n0 = (rem >> 1) * 64;
    int o0 = (rem & 1) * 64;
    int tid = threadIdx.x;
    if (tid < 64) {
        int o = o0 + tid;
        const float inv = 1.f / 4096.f;
        float m = sum[o] * inv;
        float var = fmaxf(sumsq[o] * inv - m * m, 0.f);
        float a = g[o] / sqrtf(var + EPSF);
        aL[tid] = a;
        dL[tid] = bt[o] - m * a;
    }
    __syncthreads();
    #pragma unroll
    for (int it = 0; it < 16; it++) {
        int idx = it * 256 + tid;
        int nn = idx >> 6, oo = idx & 63;
        size_t e = (size_t)(b * NPT + n0 + nn) * C2 + o0 + oo;
        float v = fmaxf(aL[oo] * h2[e] + dL[oo], 0.f);
        fp[e] = v;
        tile[nn][oo] = v;
    }
    __syncthreads();
    #pragma unroll
    for (int it = 0; it < 16; it++) {
        int idx = it * 256 + tid;
        int oo = idx >> 6, nn = idx & 63;
        size_t oi = ((size_t)(b * C2 + o0 + oo)) * NPT + n0 + nn;
        float v = tile[nn][oo];
        if (f) ((float*)out0)[oi] = v;
        else   ((unsigned short*)out0)[oi] = f2bf(v);
    }
}

// K_G: RoI voxel max-pool (unchanged).
__global__ __launch_bounds__(512) void k_pool2(const float* __restrict__ ptsf, const float* __restrict__ roisf,
                                               const float* __restrict__ fp, void* __restrict__ d_out,
                                               const void* __restrict__ Wm, int* __restrict__ glist) {
    #pragma clang fp contract(off)
    __shared__ __align__(16) int pooled[NVOX * C2];   // 64000 B
    __shared__ int cnt;
    __shared__ float rp[8];
    int f = detect_flag(Wm);
    int bid = blockIdx.x;
    int b = bid >> 7;
    int tid = threadIdx.x;
    for (int k = tid; k < NVOX * C2 / 4; k += 512) ((int4*)pooled)[k] = (int4){0, 0, 0, 0};
    if (tid == 0) {
        cnt = 0;
        size_t rb = ((size_t)bid) * 7;
        rp[0] = roisf[rb];     rp[1] = roisf[rb + 1]; rp[2] = roisf[rb + 2];
        rp[3] = roisf[rb + 3] * 0.5f;
        rp[4] = roisf[rb + 4] * 0.5f;
        rp[5] = roisf[rb + 5] * 0.5f;
        float ry = roisf[rb + 6];
        rp[6] = (float)cos((double)ry);
        rp[7] = (float)sin((double)ry);
    }
    __syncthreads();
    float cx = rp[0], cy = rp[1], cz = rp[2];
    float hx = rp[3], hy = rp[4], hz = rp[5];
    float cf = rp[6], sf = rp[7];
    int* mylist = glist + bid * NPT;
    for (int n = tid; n < NPT; n += 512) {
        size_t pb = ((size_t)(b * NPT + n)) * 3;
        float rx  = ptsf[pb]     - cx;
        float ryy = ptsf[pb + 1] - cy;
        float rz  = ptsf[pb + 2] - cz;
        float lx = rx * cf + ryy * sf;
        float ly = -rx * sf + ryy * cf;
        if (fabsf(lx) < hx && fabsf(ly) < hy && fabsf(rz) < hz) {
            int vx = (int)fminf(fmaxf(floorf((lx + hx) / (2.f * hx) * 5.f), 0.f), 4.f);
            int vy = (int)fminf(fmaxf(floorf((ly + hy) / (2.f * hy) * 5.f), 0.f), 4.f);
            int vz = (int)fminf(fmaxf(floorf((rz + hz) / (2.f * hz) * 5.f), 0.f), 4.f);
            int vox = (vx * 5 + vy) * 5 + vz;
            int pos = atomicAdd(&cnt, 1);
            mylist[pos] = (vox << 16) | n;
        }
    }
    __syncthreads();
    int m = cnt;
    int c = tid & 127, slot = tid >> 7;
    for (int e = slot; e < m; e += 4) {
        int u = mylist[e];
        int n = u & 0xFFFF, vox = u >> 16;
        float v = fp[((size_t)(b * NPT + n)) * C2 + c];
        atomicMax(&pooled[vox * C2 + c], __float_as_int(v));
    }
    __syncthreads();
    size_t ob = (size_t)524288 + (size_t)bid * (NVOX * C2);
    if (f) {
        for (int k4 = tid; k4 < NVOX * C2 / 4; k4 += 512) {
            int4 w = ((const int4*)pooled)[k4];
            float4 v = {__int_as_float(w.x), __int_as_float(w.y), __int_as_float(w.z), __int_as_float(w.w)};
            *(float4*)((float*)d_out + ob + k4 * 4) = v;
        }
    } else {
        for (int k4 = tid; k4 < NVOX * C2 / 4; k4 += 512) {
            int4 w = ((const int4*)pooled)[k4];
            ushort4 v = {f2bf(__int_as_float(w.x)), f2bf(__int_as_float(w.y)),
                         f2bf(__int_as_float(w.z)), f2bf(__int_as_float(w.w))};
            *(ushort4*)((unsigned short*)d_out + ob + k4 * 4) = v;
        }
    }
}

extern "C" void kernel_launch(void* const* d_in, const int* in_sizes, int n_in,
                              void* d_out, int out_size, void* d_ws, size_t ws_size,
                              hipStream_t stream) {
    const void* pts  = d_in[0];
    const void* feat = d_in[1];
    const void* rois = d_in[2];
    const void* Wm   = d_in[3];
    const void* gm   = d_in[4];
    const void* btm  = d_in[5];
    const void* W1   = d_in[6];
    const void* b1   = d_in[7];
    const void* g1   = d_in[8];
    const void* bt1  = d_in[9];
    const void* W2   = d_in[10];
    const void* b2   = d_in[11];
    const void* g2   = d_in[12];
    const void* bt2  = d_in[13];

    float* ws     = (float*)d_ws;
    float* ptsf   = ws + 16;
    float* roisf  = ws + 12304;
    float* params = ws + 14096;
    u16*   w1bf   = (u16*)(params + 512);
    u16*   w2bf   = (u16*)(params + 512 + 16384);
    float* wxyz   = params + 25088;
    u16*   wbf    = (u16*)(ws + 64528);
    float* stats  = ws + 101392;
    int*   idxb   = (int*)(ws + 102416);
    u16*   ftbf   = (u16*)(ws + 167952);
    float* Hmax   = ws + 1216528;
    float* Hmin   = ws + 2265104;
    float* h1     = ws + 1216528;
    float* h2     = ws + 2265104;
    float* fp     = ws + 2789392;
    float* psx    = ws + 3313680;
    float* psy    = ws + 3317776;
    float* psz    = ws + 3321872;
    float* Hf     = ws + 3325968;
    int*   glist  = (int*)(ws + 3325968);

    k_setup<<<1590, 256, 0, stream>>>(pts, feat, rois, Wm, gm, btm, W1, b1, g1, bt1,
                                      W2, b2, g2, bt2, ptsf, roisf, params,
                                      wbf, w1bf, w2bf, stats, ftbf, psx, psy, psz);
    k_qd<<<1536, 256, 0, stream>>>(psx, psy, psz, idxb, ftbf, wbf, Hf);
    k_gather<<<(NB * NPT) / GPTS, 256, 0, stream>>>(Hf, idxb, ptsf, wxyz, Hmax, Hmin, stats);
    k_lin1f<<<256, 256, 0, stream>>>(Hmax, Hmin, stats, params + 0, params + 256,
                                     w1bf, params + 33280, h1, stats + 512, stats + 640);
    k_lin2f<<<256, 256, 0, stream>>>(h1, stats + 512, params + 33408, params + 33536,
                                     w2bf, params + 50048, h2, stats + 768, stats + 896);
    k_final2<<<128, 256, 0, stream>>>(h2, stats + 768, stats + 896,
                                      params + 50176, params + 50304, fp, d_out, Wm);
    k_pool2<<<NB * NROI, 512, 0, stream>>>(ptsf, roisf, fp, d_out, Wm, glist);
}

// Round 14
// 184.833 us; speedup vs baseline: 1.1409x; 1.0277x over previous
//
#include <hip/hip_runtime.h>
#include <hip/hip_bf16.h>

typedef __hip_bfloat16 bf16;
typedef unsigned short u16;

#define NB   2
#define NPT  2048
#define NROI 128
#define CINF 256
#define NS   16
#define KDIM 259     // CIN + 3
#define KP2  288     // W_mlp repack stride (cols 0..255 feat, 256..258 xyz, pad)
#define C1   256     // mlp out channels
#define C2   128     // layer1/2 out channels
#define NVOX 125
#define EPSF 1e-5f

typedef __bf16 bf16x8 __attribute__((ext_vector_type(8)));
typedef float  f32x4  __attribute__((ext_vector_type(4)));

__device__ __forceinline__ float ldin(const void* p, size_t i, int f32flag) {
    if (f32flag) return ((const float*)p)[i];
    unsigned short u = ((const unsigned short*)p)[i];
    return __uint_as_float(((unsigned)u) << 16);
}

__device__ __forceinline__ unsigned short f2bf(float x) {
    unsigned u = __float_as_uint(x);
    u += 0x7FFFu + ((u >> 16) & 1u);
    return (unsigned short)(u >> 16);
}

// Inline dtype detect (uniform across threads; see R10 notes).
__device__ __forceinline__ int detect_flag(const void* __restrict__ Wm) {
    const uint4* p = (const uint4*)Wm;
    int bad = 0;
    #pragma unroll
    for (int i = 0; i < 8; i++) {
        uint4 v = p[i];
        unsigned w[4] = {v.x, v.y, v.z, v.w};
        #pragma unroll
        for (int j = 0; j < 4; j++) {
            if (!(fabsf(__uint_as_float(w[j] << 16)) <= 1e4f)) bad = 1;
            if (!(fabsf(__uint_as_float(w[j] & 0xFFFF0000u)) <= 1e4f)) bad = 1;
        }
    }
    return bad;
}

// ---------------- ws layout (float units), total 4,374,544 f = 17.5 MB ----------------
// ptsf@16  roisf@12304  params@14096  Wbf@64528  stats@101392  idxb@102416
// ftbf@167952  Hmax@1216528(h1 overlays)  Hmin@2265104(h2 overlays; fp@2789392)
// psx@3313680 psy@3317776 psz@3321872  Hf@3325968 (glist overlays)

// K_A: fused setup (unchanged)
__global__ __launch_bounds__(256) void k_setup(
    const void* __restrict__ pts, const void* __restrict__ feat, const void* __restrict__ rois,
    const void* __restrict__ Wm, const void* __restrict__ gm, const void* __restrict__ btm,
    const void* __restrict__ W1, const void* __restrict__ b1, const void* __restrict__ g1,
    const void* __restrict__ bt1, const void* __restrict__ W2, const void* __restrict__ b2,
    const void* __restrict__ g2, const void* __restrict__ bt2,
    float* __restrict__ ptsf, float* __restrict__ roisf, float* __restrict__ params,
    u16* __restrict__ wbf, u16* __restrict__ w1bf, u16* __restrict__ w2bf,
    float* __restrict__ stats, u16* __restrict__ ftbf,
    float* __restrict__ psx, float* __restrict__ psy, float* __restrict__ psz) {
    int f = detect_flag(Wm);
    int bx = blockIdx.x;
    int tid = threadIdx.x;
    if (bx < 1024) {
        __shared__ float tile[32][33];
        int b = bx >> 9;
        int r = bx & 511;
        int n0 = (r & 63) * 32, c0 = (r >> 6) * 32;
        int tx = tid & 31, ty = tid >> 5;
        #pragma unroll
        for (int d = 0; d < 4; d++) {
            int c = c0 + ty + d * 8;
            tile[ty + d * 8][tx] = ldin(feat, ((size_t)(b * CINF + c)) * NPT + n0 + tx, f);
        }
        __syncthreads();
        #pragma unroll
        for (int d = 0; d < 4; d++) {
            int n = n0 + ty + d * 8;
            ftbf[((size_t)(b * NPT + n)) * CINF + c0 + tx] = f2bf(tile[tx][ty + d * 8]);
        }
    } else if (bx < 1312) {
        int e = (bx - 1024) * 256 + tid;
        int o = e / KP2, k = e % KP2;
        float v = 0.f;
        if (k < 256)      v = ldin(Wm, (size_t)o * KDIM + 3 + k, f);
        else if (k < 259) v = ldin(Wm, (size_t)o * KDIM + (k - 256), f);
        wbf[e] = f2bf(v);
    } else if (bx < 1440) {
        int e = (bx - 1312) * 256 + tid;
        w1bf[e] = f2bf(ldin(W1, e, f));
    } else if (bx < 1504) {
        int e = (bx - 1440) * 256 + tid;
        w2bf[e] = f2bf(ldin(W2, e, f));
    } else if (bx < 1552) {
        int e = (bx - 1504) * 256 + tid;
        if (e < NB * NPT * 3) ptsf[e] = ldin(pts, e, f);
    } else if (bx < 1559) {
        int e = (bx - 1552) * 256 + tid;
        if (e < NB * NROI * 7) roisf[e] = ldin(rois, e, f);
    } else if (bx < 1567) {
        int t = bx - 1559;
        const void* src; int off, n;
        switch (t) {
            case 0: src = gm;  off = 0;     n = 256; break;
            case 1: src = btm; off = 256;   n = 256; break;
            case 2: src = b1;  off = 33280; n = 128; break;
            case 3: src = g1;  off = 33408; n = 128; break;
            case 4: src = bt1; off = 33536; n = 128; break;
            case 5: src = b2;  off = 50048; n = 128; break;
            case 6: src = g2;  off = 50176; n = 128; break;
            default: src = bt2; off = 50304; n = 128; break;
        }
        if (tid < n) params[off + tid] = ldin(src, tid, f);
    } else if (bx < 1570) {
        int e = (bx - 1567) * 256 + tid;
        if (e < 768) {
            int d = e >> 8, o = e & 255;
            params[25088 + e] = ldin(Wm, (size_t)o * KDIM + d, f);
        }
    } else if (bx < 1586) {
        int e = (bx - 1570) * 256 + tid;
        if (e < NB * NPT) {
            psx[e] = ldin(pts, e * 3 + 0, f);
            psy[e] = ldin(pts, e * 3 + 1, f);
            psz[e] = ldin(pts, e * 3 + 2, f);
        }
    } else {
        int e = (bx - 1586) * 256 + tid;
        if (e < 1024) stats[e] = 0.f;
    }
}

// K_B: fused ball-query (with early exit) + dense GEMM (unchanged).
__global__ __launch_bounds__(256) void k_qd(const float* __restrict__ psx, const float* __restrict__ psy,
                                            const float* __restrict__ psz, int* __restrict__ idxb,
                                            const u16* __restrict__ ftbf, const u16* __restrict__ wbf,
                                            float* __restrict__ Hf) {
    int bx = blockIdx.x;
    if (bx < 1024) {
        #pragma clang fp contract(off)
        int wid = threadIdx.x >> 6, lane = threadIdx.x & 63;
        int q = bx * 4 + wid;
        int b = q >> 11;
        int base = b * NPT;
        float qx = psx[q], qy = psy[q], qz = psz[q];
        const float R2 = (float)(0.3 * 0.3);
        size_t ob = (size_t)q * NS;
        int cnt = 0, j0 = -1;
        unsigned long long below = (lane == 63) ? ~0ull >> 1 : ((1ull << (lane + 1)) - 1) >> 1;
        for (int c0 = 0; c0 < NPT; c0 += 64) {
            int j = c0 + lane;
            float dx = qx - psx[base + j];
            float dy = qy - psy[base + j];
            float dz = qz - psz[base + j];
            float d2 = dx * dx + dy * dy + dz * dz;
            bool hit = d2 < R2;
            unsigned long long m = __ballot(hit);
            if (m) {
                if (j0 < 0) j0 = c0 + __builtin_ctzll(m);
                int pos = cnt + __popcll(m & below);
                if (hit && pos < NS) idxb[ob + pos] = j;
                cnt += __popcll(m);
            }
            if (cnt >= NS) break;
        }
        if (lane >= cnt && lane < NS) idxb[ob + lane] = j0;
    } else {
        int bx2 = bx - 1024;
        int w = threadIdx.x >> 6, lane = threadIdx.x & 63;
        int lg = lane >> 4, lr = lane & 15;
        int rbase = (bx2 & 255) * 16;
        int c0 = (bx2 >> 8) * 128 + w * 32;

        size_t aoff  = (size_t)(rbase + lr) * CINF + lg * 8;
        size_t boff0 = (size_t)(c0 + lr) * KP2 + lg * 8;
        size_t boff1 = (size_t)(c0 + 16 + lr) * KP2 + lg * 8;

        f32x4 acc0 = (f32x4){0.f, 0.f, 0.f, 0.f};
        f32x4 acc1 = (f32x4){0.f, 0.f, 0.f, 0.f};
        #pragma unroll
        for (int k0 = 0; k0 < 256; k0 += 32) {
            bf16x8 af = __builtin_bit_cast(bf16x8, *(const uint4*)(ftbf + aoff + k0));
            bf16x8 b0 = __builtin_bit_cast(bf16x8, *(const uint4*)(wbf + boff0 + k0));
            bf16x8 b1 = __builtin_bit_cast(bf16x8, *(const uint4*)(wbf + boff1 + k0));
            acc0 = __builtin_amdgcn_mfma_f32_16x16x32_bf16(af, b0, acc0, 0, 0, 0);
            acc1 = __builtin_amdgcn_mfma_f32_16x16x32_bf16(af, b1, acc1, 0, 0, 0);
        }
        #pragma unroll
        for (int r = 0; r < 4; r++) {
            int row = rbase + lg * 4 + r;
            Hf[(size_t)row * C1 + c0 + lr] = acc0[r];
            Hf[(size_t)row * C1 + c0 + 16 + lr] = acc1[r];
        }
    }
}

// K_C: gather-reduce, s-outer / p-inner; s-loop unrolled 4x -> up to 32
// independent Hf loads in flight per wave (was 8). FP update order per point
// preserved (unroll keeps iteration order for the dependent accumulators).
#define GPTS 8
__global__ __launch_bounds__(256) void k_gather(const float* __restrict__ Hf, const int* __restrict__ idxb,
                                                const float* __restrict__ ptsf, const float* __restrict__ wxyz,
                                                float* __restrict__ Hmax, float* __restrict__ Hmin,
                                                float* __restrict__ stats) {
    int o = threadIdx.x;
    float wx = wxyz[o], wy = wxyz[256 + o], wz = wxyz[512 + o];
    int pt0 = blockIdx.x * GPTS;
    int b = pt0 >> 11;
    int base = b * NPT;
    float cx[GPTS], cy[GPTS], cz[GPTS];
    float mx[GPTS], mn[GPTS], sm[GPTS], sq[GPTS];
    #pragma unroll
    for (int p = 0; p < GPTS; p++) {
        size_t cb = (size_t)(pt0 + p) * 3;
        cx[p] = ptsf[cb]; cy[p] = ptsf[cb + 1]; cz[p] = ptsf[cb + 2];
        mx[p] = -3.4e38f; mn[p] = 3.4e38f; sm[p] = 0.f; sq[p] = 0.f;
    }
    #pragma unroll 4
    for (int s = 0; s < NS; s++) {
        int jj[GPTS];
        float v[GPTS];
        #pragma unroll
        for (int p = 0; p < GPTS; p++)
            jj[p] = idxb[(size_t)(pt0 + p) * NS + s];          // uniform -> scalar loads
        #pragma unroll
        for (int p = 0; p < GPTS; p++)
            v[p] = Hf[(size_t)(base + jj[p]) * C1 + o];        // independent vector loads
        #pragma unroll
        for (int p = 0; p < GPTS; p++) {
            size_t jb = ((size_t)(base + jj[p])) * 3;
            float gx = (ptsf[jb]     - cx[p]) / 0.3f;
            float gy = (ptsf[jb + 1] - cy[p]) / 0.3f;
            float gz = (ptsf[jb + 2] - cz[p]) / 0.3f;
            float t = v[p] + wx * gx + wy * gy + wz * gz;
            mx[p] = fmaxf(mx[p], t); mn[p] = fminf(mn[p], t);
            sm[p] += t; sq[p] += t * t;
        }
    }
    float ssum = 0.f, ssq = 0.f;
    #pragma unroll
    for (int p = 0; p < GPTS; p++) {
        Hmax[(size_t)(pt0 + p) * C1 + o] = mx[p];
        Hmin[(size_t)(pt0 + p) * C1 + o] = mn[p];
        ssum += sm[p]; ssq += sq[p];
    }
    atomicAdd(&stats[o], ssum);
    atomicAdd(&stats[256 + o], ssq);
}

// K_D: layer1 GEMM with fused feats0 prologue (unchanged).
__global__ __launch_bounds__(256) void k_lin1f(const float* __restrict__ Hmax, const float* __restrict__ Hmin,
                                               const float* __restrict__ stats, const float* __restrict__ g,
                                               const float* __restrict__ bt, const u16* __restrict__ Wb,
                                               const float* __restrict__ bias, float* __restrict__ out,
                                               float* __restrict__ sum, float* __restrict__ sumsq) {
    __shared__ __align__(16) u16 xa[16][264];
    int tid = threadIdx.x;
    int rbase = blockIdx.x * 16;
    {
        int c = tid;
        const float inv = 1.f / 65536.f;
        float m = stats[c] * inv;
        float var = fmaxf(stats[256 + c] * inv - m * m, 0.f);
        float a = g[c] / sqrtf(var + EPSF);
        float d = bt[c] - m * a;
        #pragma unroll
        for (int r = 0; r < 16; r++) {
            size_t e = (size_t)(rbase + r) * C1 + c;
            float h = (a > 0.f) ? Hmax[e] : Hmin[e];
            xa[r][c] = f2bf(fmaxf(a * h + d, 0.f));
        }
    }
    __syncthreads();
    int w = tid >> 6, lane = tid & 63;
    int lg = lane >> 4, lr = lane & 15;
    int c0 = w * 32;
    size_t boff0 = (size_t)(c0 + lr) * 256 + lg * 8;
    size_t boff1 = (size_t)(c0 + 16 + lr) * 256 + lg * 8;

    f32x4 acc0 = (f32x4){0.f, 0.f, 0.f, 0.f};
    f32x4 acc1 = (f32x4){0.f, 0.f, 0.f, 0.f};
    #pragma unroll
    for (int k0 = 0; k0 < 256; k0 += 32) {
        bf16x8 af = __builtin_bit_cast(bf16x8, *(const uint4*)&xa[lr][k0 + lg * 8]);
        bf16x8 b0 = __builtin_bit_cast(bf16x8, *(const uint4*)(Wb + boff0 + k0));
        bf16x8 b1 = __builtin_bit_cast(bf16x8, *(const uint4*)(Wb + boff1 + k0));
        acc0 = __builtin_amdgcn_mfma_f32_16x16x32_bf16(af, b0, acc0, 0, 0, 0);
        acc1 = __builtin_amdgcn_mfma_f32_16x16x32_bf16(af, b1, acc1, 0, 0, 0);
    }
    #pragma unroll
    for (int ct = 0; ct < 2; ct++) {
        f32x4 a = ct ? acc1 : acc0;
        int col = c0 + ct * 16 + lr;
        float bi = bias[col];
        float s = 0.f, q = 0.f;
        #pragma unroll
        for (int r = 0; r < 4; r++) {
            float h = a[r] + bi;
            out[(size_t)(rbase + lg * 4 + r) * C2 + col] = h;
            s += h; q += h * h;
        }
        s += __shfl_xor(s, 16); s += __shfl_xor(s, 32);
        q += __shfl_xor(q, 16); q += __shfl_xor(q, 32);
        if (lane < 16) {
            atomicAdd(&sum[col], s);
            atomicAdd(&sumsq[col], q);
        }
    }
}

// K_E: layer2 GEMM with fused bnrelu prologue (unchanged).
__global__ __launch_bounds__(256) void k_lin2f(const float* __restrict__ h1, const float* __restrict__ stats1,
                                               const float* __restrict__ g, const float* __restrict__ bt,
                                               const u16* __restrict__ Wb, const float* __restrict__ bias,
                                               float* __restrict__ out, float* __restrict__ sum,
                                               float* __restrict__ sumsq) {
    __shared__ __align__(16) u16 xa[16][136];
    int tid = threadIdx.x;
    int rbase = blockIdx.x * 16;
    {
        int c = tid & 127, half = tid >> 7;
        const float inv = 1.f / 4096.f;
        float m = stats1[c] * inv;
        float var = fmaxf(stats1[128 + c] * inv - m * m, 0.f);
        float a = g[c] / sqrtf(var + EPSF);
        float d = bt[c] - m * a;
        #pragma unroll
        for (int rr = 0; rr < 8; rr++) {
            int r = half * 8 + rr;
            float h = h1[(size_t)(rbase + r) * C2 + c];
            xa[r][c] = f2bf(fmaxf(a * h + d, 0.f));
        }
    }
    __syncthreads();
    int w = tid >> 6, lane = tid & 63;
    int lg = lane >> 4, lr = lane & 15;
    int c0 = w * 32;
    size_t boff0 = (size_t)(c0 + lr) * 128 + lg * 8;
    size_t boff1 = (size_t)(c0 + 16 + lr) * 128 + lg * 8;

    f32x4 acc0 = (f32x4){0.f, 0.f, 0.f, 0.f};
    f32x4 acc1 = (f32x4){0.f, 0.f, 0.f, 0.f};
    #pragma unroll
    for (int k0 = 0; k0 < 128; k0 += 32) {
        bf16x8 af = __builtin_bit_cast(bf16x8, *(const uint4*)&xa[lr][k0 + lg * 8]);
        bf16x8 b0 = __builtin_bit_cast(bf16x8, *(const uint4*)(Wb + boff0 + k0));
        bf16x8 b1 = __builtin_bit_cast(bf16x8, *(const uint4*)(Wb + boff1 + k0));
        acc0 = __builtin_amdgcn_mfma_f32_16x16x32_bf16(af, b0, acc0, 0, 0, 0);
        acc1 = __builtin_amdgcn_mfma_f32_16x16x32_bf16(af, b1, acc1, 0, 0, 0);
    }
    #pragma unroll
    for (int ct = 0; ct < 2; ct++) {
        f32x4 a = ct ? acc1 : acc0;
        int col = c0 + ct * 16 + lr;
        float bi = bias[col];
        float s = 0.f, q = 0.f;
        #pragma unroll
        for (int r = 0; r < 4; r++) {
            float h = a[r] + bi;
            out[(size_t)(rbase + lg * 4 + r) * C2 + col] = h;
            s += h; q += h * h;
        }
        s += __shfl_xor(s, 16); s += __shfl_xor(s, 32);
        q += __shfl_xor(q, 16); q += __shfl_xor(q, 32);
        if (lane < 16) {
            atomicAdd(&sum[col], s);
            atomicAdd(&sumsq[col], q);
        }
    }
}

// K_F v2: relu(BN(h2)) with LDS-transposed out0 write (unchanged).
__global__ __launch_bounds__(256) void k_final2(const float* __restrict__ h2, const float* __restrict__ sum,
                                                const float* __restrict__ sumsq, const float* __restrict__ g,
                                                const float* __restrict__ bt, float* __restrict__ fp,
                                                void* __restrict__ out0, const void* __restrict__ Wm) {
    __shared__ float tile[64][65];
    __shared__ float aL[64], dL[64];
    int f = detect_flag(Wm);
    int bx = blockIdx.x;
    int b = bx >> 6;
    int rem = bx & 63;
    int n0 = (rem >> 1) * 64;
    int o0 = (rem & 1) * 64;
    int tid = threadIdx.x;
    if (tid < 64) {
        int o = o0 + tid;
        const float inv = 1.f / 4096.f;
        float m = sum[o] * inv;
        float var = fmaxf(sumsq[o] * inv - m * m, 0.f);
        float a = g[o] / sqrtf(var + EPSF);
        aL[tid] = a;
        dL[tid] = bt[o] - m * a;
    }
    __syncthreads();
    #pragma unroll
    for (int it = 0; it < 16; it++) {
        int idx = it * 256 + tid;
        int nn = idx >> 6, oo = idx & 63;
        size_t e = (size_t)(b * NPT + n0 + nn) * C2 + o0 + oo;
        float v = fmaxf(aL[oo] * h2[e] + dL[oo], 0.f);
        fp[e] = v;
        tile[nn][oo] = v;
    }
    __syncthreads();
    #pragma unroll
    for (int it = 0; it < 16; it++) {
        int idx = it * 256 + tid;
        int oo = idx >> 6, nn = idx & 63;
        size_t oi = ((size_t)(b * C2 + o0 + oo)) * NPT + n0 + nn;
        float v = tile[nn][oo];
        if (f) ((float*)out0)[oi] = v;
        else   ((unsigned short*)out0)[oi] = f2bf(v);
    }
}

// K_G: RoI voxel max-pool; list-consume loop software-pipelined 2-deep so the
// mylist->fp->atomicMax dependent chain overlaps across iterations.
__global__ __launch_bounds__(512) void k_pool2(const float* __restrict__ ptsf, const float* __restrict__ roisf,
                                               const float* __restrict__ fp, void* __restrict__ d_out,
                                               const void* __restrict__ Wm, int* __restrict__ glist) {
    #pragma clang fp contract(off)
    __shared__ __align__(16) int pooled[NVOX * C2];   // 64000 B
    __shared__ int cnt;
    __shared__ float rp[8];
    int f = detect_flag(Wm);
    int bid = blockIdx.x;
    int b = bid >> 7;
    int tid = threadIdx.x;
    for (int k = tid; k < NVOX * C2 / 4; k += 512) ((int4*)pooled)[k] = (int4){0, 0, 0, 0};
    if (tid == 0) {
        cnt = 0;
        size_t rb = ((size_t)bid) * 7;
        rp[0] = roisf[rb];     rp[1] = roisf[rb + 1]; rp[2] = roisf[rb + 2];
        rp[3] = roisf[rb + 3] * 0.5f;
        rp[4] = roisf[rb + 4] * 0.5f;
        rp[5] = roisf[rb + 5] * 0.5f;
        float ry = roisf[rb + 6];
        rp[6] = (float)cos((double)ry);
        rp[7] = (float)sin((double)ry);
    }
    __syncthreads();
    float cx = rp[0], cy = rp[1], cz = rp[2];
    float hx = rp[3], hy = rp[4], hz = rp[5];
    float cf = rp[6], sf = rp[7];
    int* mylist = glist + bid * NPT;
    for (int n = tid; n < NPT; n += 512) {
        size_t pb = ((size_t)(b * NPT + n)) * 3;
        float rx  = ptsf[pb]     - cx;
        float ryy = ptsf[pb + 1] - cy;
        float rz  = ptsf[pb + 2] - cz;
        float lx = rx * cf + ryy * sf;
        float ly = -rx * sf + ryy * cf;
        if (fabsf(lx) < hx && fabsf(ly) < hy && fabsf(rz) < hz) {
            int vx = (int)fminf(fmaxf(floorf((lx + hx) / (2.f * hx) * 5.f), 0.f), 4.f);
            int vy = (int)fminf(fmaxf(floorf((ly + hy) / (2.f * hy) * 5.f), 0.f), 4.f);
            int vz = (int)fminf(fmaxf(floorf((rz + hz) / (2.f * hz) * 5.f), 0.f), 4.f);
            int vox = (vx * 5 + vy) * 5 + vz;
            int pos = atomicAdd(&cnt, 1);
            mylist[pos] = (vox << 16) | n;
        }
    }
    __syncthreads();
    int m = cnt;
    int c = tid & 127, slot = tid >> 7;
    {
        int e = slot;
        int u = (e < m) ? mylist[e] : 0;
        float v = (e < m) ? fp[((size_t)(b * NPT + (u & 0xFFFF))) * C2 + c] : 0.f;
        while (e < m) {
            int e2 = e + 4;
            int u2 = 0; float v2 = 0.f;
            if (e2 < m) {
                u2 = mylist[e2];
                v2 = fp[((size_t)(b * NPT + (u2 & 0xFFFF))) * C2 + c];   // issued before atomic
            }
            atomicMax(&pooled[(u >> 16) * C2 + c], __float_as_int(v));
            e = e2; u = u2; v = v2;
        }
    }
    __syncthreads();
    size_t ob = (size_t)524288 + (size_t)bid * (NVOX * C2);
    if (f) {
        for (int k4 = tid; k4 < NVOX * C2 / 4; k4 += 512) {
            int4 w = ((const int4*)pooled)[k4];
            float4 v = {__int_as_float(w.x), __int_as_float(w.y), __int_as_float(w.z), __int_as_float(w.w)};
            *(float4*)((float*)d_out + ob + k4 * 4) = v;
        }
    } else {
        for (int k4 = tid; k4 < NVOX * C2 / 4; k4 += 512) {
            int4 w = ((const int4*)pooled)[k4];
            ushort4 v = {f2bf(__int_as_float(w.x)), f2bf(__int_as_float(w.y)),
                         f2bf(__int_as_float(w.z)), f2bf(__int_as_float(w.w))};
            *(ushort4*)((unsigned short*)d_out + ob + k4 * 4) = v;
        }
    }
}

extern "C" void kernel_launch(void* const* d_in, const int* in_sizes, int n_in,
                              void* d_out, int out_size, void* d_ws, size_t ws_size,
                              hipStream_t stream) {
    const void* pts  = d_in[0];
    const void* feat = d_in[1];
    const void* rois = d_in[2];
    const void* Wm   = d_in[3];
    const void* gm   = d_in[4];
    const void* btm  = d_in[5];
    const void* W1   = d_in[6];
    const void* b1   = d_in[7];
    const void* g1   = d_in[8];
    const void* bt1  = d_in[9];
    const void* W2   = d_in[10];
    const void* b2   = d_in[11];
    const void* g2   = d_in[12];
    const void* bt2  = d_in[13];

    float* ws     = (float*)d_ws;
    float* ptsf   = ws + 16;
    float* roisf  = ws + 12304;
    float* params = ws + 14096;
    u16*   w1bf   = (u16*)(params + 512);
    u16*   w2bf   = (u16*)(params + 512 + 16384);
    float* wxyz   = params + 25088;
    u16*   wbf    = (u16*)(ws + 64528);
    float* stats  = ws + 101392;
    int*   idxb   = (int*)(ws + 102416);
    u16*   ftbf   = (u16*)(ws + 167952);
    float* Hmax   = ws + 1216528;
    float* Hmin   = ws + 2265104;
    float* h1     = ws + 1216528;
    float* h2     = ws + 2265104;
    float* fp     = ws + 2789392;
    float* psx    = ws + 3313680;
    float* psy    = ws + 3317776;
    float* psz    = ws + 3321872;
    float* Hf     = ws + 3325968;
    int*   glist  = (int*)(ws + 3325968);

    k_setup<<<1590, 256, 0, stream>>>(pts, feat, rois, Wm, gm, btm, W1, b1, g1, bt1,
                                      W2, b2, g2, bt2, ptsf, roisf, params,
                                      wbf, w1bf, w2bf, stats, ftbf, psx, psy, psz);
    k_qd<<<1536, 256, 0, stream>>>(psx, psy, psz, idxb, ftbf, wbf, Hf);
    k_gather<<<(NB * NPT) / GPTS, 256, 0, stream>>>(Hf, idxb, ptsf, wxyz, Hmax, Hmin, stats);
    k_lin1f<<<256, 256, 0, stream>>>(Hmax, Hmin, stats, params + 0, params + 256,
                                     w1bf, params + 33280, h1, stats + 512, stats + 640);
    k_lin2f<<<256, 256, 0, stream>>>(h1, stats + 512, params + 33408, params + 33536,
                                     w2bf, params + 50048, h2, stats + 768, stats + 896);
    k_final2<<<128, 256, 0, stream>>>(h2, stats + 768, stats + 896,
                                      params + 50176, params + 50304, fp, d_out, Wm);
    k_pool2<<<NB * NROI, 512, 0, stream>>>(ptsf, roisf, fp, d_out, Wm, glist);
}